// Round 2
// baseline (149.840 us; speedup 1.0000x reference)
//
#include <hip/hip_runtime.h>
#include <hip/hip_bf16.h>

typedef unsigned short u16;
typedef __attribute__((ext_vector_type(8))) short bf16x8;
typedef __attribute__((ext_vector_type(4))) float f32x4;
typedef __attribute__((ext_vector_type(4))) u16 u16x4;

#define N 4096
#define F 128
#define H 4
#define O 64

__device__ inline u16 f2bf(float f) {
  union { float f; unsigned u; } v; v.f = f;
  unsigned r = (v.u + 0x7fffu + ((v.u >> 16) & 1u)) >> 16;
  return (u16)r;
}

// ---------------------------------------------------------------------------
// Projections in fp32 (error ~1e-6), outputs rounded to bf16.
// Q[h][n][64], K[h][m][64] row-major; V stored transposed Vt[h][o][m].
// grid (N/64, 12): y = h*3 + {0:Q,1:K,2:V}
// ---------------------------------------------------------------------------
__global__ __launch_bounds__(256) void proj_kernel(
    const float* __restrict__ x, const float* __restrict__ wv,
    const float* __restrict__ wq, const float* __restrict__ wk,
    u16* __restrict__ Q, u16* __restrict__ K, u16* __restrict__ Vt) {
  __shared__ float xs[64][132];   // +4 pad: row stride 132 -> <=2-way banks on column reads
  __shared__ float wsh[128][64];
  const int t = threadIdx.x;
  const int brow = blockIdx.x * 64;
  const int p = blockIdx.y, h = p / 3, which = p % 3;
  const float* W = (which == 0 ? wq : which == 1 ? wk : wv) + h * F * O;

#pragma unroll
  for (int i = 0; i < 8; i++) {           // x tile: 64 x 128 fp32 = 2048 float4
    int idx = t + i * 256, r = idx >> 5, c4 = idx & 31;
    *(float4*)&xs[r][c4 * 4] = *(const float4*)&x[(brow + r) * F + c4 * 4];
  }
#pragma unroll
  for (int i = 0; i < 8; i++) {           // W tile: 128 x 64 fp32 = 2048 float4
    int idx = t + i * 256, r = idx >> 4, c4 = idx & 15;
    *(float4*)&wsh[r][c4 * 4] = *(const float4*)&W[r * O + c4 * 4];
  }
  __syncthreads();

  const int r0 = (t >> 4) << 2, c0 = (t & 15) << 2;
  float acc[4][4] = {};
#pragma unroll 8
  for (int f = 0; f < F; f++) {
    float4 b = *(float4*)&wsh[f][c0];
    float a0 = xs[r0 + 0][f], a1 = xs[r0 + 1][f];
    float a2 = xs[r0 + 2][f], a3 = xs[r0 + 3][f];
    acc[0][0] = fmaf(a0, b.x, acc[0][0]); acc[0][1] = fmaf(a0, b.y, acc[0][1]);
    acc[0][2] = fmaf(a0, b.z, acc[0][2]); acc[0][3] = fmaf(a0, b.w, acc[0][3]);
    acc[1][0] = fmaf(a1, b.x, acc[1][0]); acc[1][1] = fmaf(a1, b.y, acc[1][1]);
    acc[1][2] = fmaf(a1, b.z, acc[1][2]); acc[1][3] = fmaf(a1, b.w, acc[1][3]);
    acc[2][0] = fmaf(a2, b.x, acc[2][0]); acc[2][1] = fmaf(a2, b.y, acc[2][1]);
    acc[2][2] = fmaf(a2, b.z, acc[2][2]); acc[2][3] = fmaf(a2, b.w, acc[2][3]);
    acc[3][0] = fmaf(a3, b.x, acc[3][0]); acc[3][1] = fmaf(a3, b.y, acc[3][1]);
    acc[3][2] = fmaf(a3, b.z, acc[3][2]); acc[3][3] = fmaf(a3, b.w, acc[3][3]);
  }

  if (which < 2) {
    u16* dst = (which == 0 ? Q : K) + h * N * O;
#pragma unroll
    for (int i = 0; i < 4; i++) {
      u16x4 v4 = { f2bf(acc[i][0]), f2bf(acc[i][1]), f2bf(acc[i][2]), f2bf(acc[i][3]) };
      *(u16x4*)&dst[(brow + r0 + i) * O + c0] = v4;
    }
  } else {
    u16* dst = Vt + h * O * N;  // transposed store: Vt[o][n]
#pragma unroll
    for (int j = 0; j < 4; j++) {
      u16x4 v4 = { f2bf(acc[0][j]), f2bf(acc[1][j]), f2bf(acc[2][j]), f2bf(acc[3][j]) };
      *(u16x4*)&dst[(c0 + j) * N + brow + r0] = v4;
    }
  }
}

// ---------------------------------------------------------------------------
// row_mask[n] = any(x[n][f] != 0)
// ---------------------------------------------------------------------------
__global__ __launch_bounds__(256) void mask_kernel(const float* __restrict__ x,
                                                   float* __restrict__ mask) {
  int n = blockIdx.x * 256 + threadIdx.x;
  const float4* xr = (const float4*)(x + n * F);
  float s = 0.f;
#pragma unroll
  for (int i = 0; i < F / 4; i++) {
    float4 v = xr[i];
    s += fabsf(v.x) + fabsf(v.y) + fabsf(v.z) + fabsf(v.w);
  }
  mask[n] = (s != 0.f) ? 1.f : 0.f;
}

// ---------------------------------------------------------------------------
// Fused masked attention + aggregation + epilogue.
// grid (N/16, H), block 256 (4 waves). Each wave: 16 rows x 1024-col chunk,
// flash online softmax; block merges the 4 column partials in LDS.
// MFMA 16x16x32 bf16. C/D layout: row=(l>>4)*4+r, col=l&15 (verified m89).
// ---------------------------------------------------------------------------
__global__ __launch_bounds__(256) void attn_kernel(
    const float* __restrict__ adj, const u16* __restrict__ Qg,
    const u16* __restrict__ Kg, const u16* __restrict__ Vtg,
    const float* __restrict__ rowmask, float* __restrict__ out) {
  __shared__ u16 p_lds[4][16][72];   // per-wave P staging, stride 144B (16B-aligned)
  __shared__ float Om[4][16][64];    // per-wave partial O
  __shared__ float Ms[4][16];        // per-wave running max
  __shared__ float Ss[4][16];        // per-wave running sum

  const int tid = threadIdx.x;
  const int w = tid >> 6, l = tid & 63;
  const int lm = l & 15, lg = l >> 4;
  const int h = blockIdx.y;
  const int R0 = blockIdx.x * 16;

  const u16* Qh = Qg + h * N * O;
  const u16* Kh = Kg + h * N * O;
  const u16* Vth = Vtg + h * O * N;

  // Q fragments (held for the whole kernel): A[m=lm][k=lg*8+j]
  bf16x8 qa0 = *(const bf16x8*)&Qh[(R0 + lm) * O + lg * 8];
  bf16x8 qa1 = *(const bf16x8*)&Qh[(R0 + lm) * O + 32 + lg * 8];

  f32x4 oacc[4];
  float mrow[4], srow[4];
#pragma unroll
  for (int i = 0; i < 4; i++) {
    oacc[i] = (f32x4){0.f, 0.f, 0.f, 0.f};
    mrow[i] = -1e30f;
    srow[i] = 0.f;
  }
  const f32x4 zero4 = {0.f, 0.f, 0.f, 0.f};

  for (int it = 0; it < 16; ++it) {
    const int cb = w * 1024 + it * 64;

    // ---- S = Q K^T (4 col-tiles x K=64) ----
    f32x4 sacc[4];
#pragma unroll
    for (int tt = 0; tt < 4; tt++) {
      bf16x8 kb0 = *(const bf16x8*)&Kh[(cb + tt * 16 + lm) * O + lg * 8];
      bf16x8 kb1 = *(const bf16x8*)&Kh[(cb + tt * 16 + lm) * O + 32 + lg * 8];
      f32x4 s0 = __builtin_amdgcn_mfma_f32_16x16x32_bf16(qa0, kb0, zero4, 0, 0, 0);
      sacc[tt] = __builtin_amdgcn_mfma_f32_16x16x32_bf16(qa1, kb1, s0, 0, 0, 0);
    }

    // ---- mask + LeakyReLU + /sqrt(D); masked -> -1e30 (== reference -1e9 path) ----
    float pv[4][4];                   // [tile][r] logits, then probabilities
    float bmax[4] = {-1e30f, -1e30f, -1e30f, -1e30f};
#pragma unroll
    for (int tt = 0; tt < 4; tt++) {
#pragma unroll
      for (int r = 0; r < 4; r++) {
        int row = R0 + lg * 4 + r;
        float av = adj[row * N + cb + tt * 16 + lm];
        float sv = sacc[tt][r];
        float lv = (sv < 0.f ? 0.2f * sv : sv) * 0.125f;  // leaky(0.2), /sqrt(64)
        lv = (av != 0.f) ? lv : -1e30f;
        pv[tt][r] = lv;
        bmax[r] = fmaxf(bmax[r], lv);
      }
    }
    // row-max across the 16 lanes holding this row's columns
#pragma unroll
    for (int r = 0; r < 4; r++) {
      float b = bmax[r];
      b = fmaxf(b, __shfl_xor(b, 1));
      b = fmaxf(b, __shfl_xor(b, 2));
      b = fmaxf(b, __shfl_xor(b, 4));
      b = fmaxf(b, __shfl_xor(b, 8));
      bmax[r] = b;
    }
    float scale[4];
#pragma unroll
    for (int r = 0; r < 4; r++) {
      float mn = fmaxf(mrow[r], bmax[r]);
      scale[r] = __expf(mrow[r] - mn);   // old=-1e30 -> 0; both -1e30 -> exp(0)=1, srow stays 0
      mrow[r] = mn;
    }
    // probabilities + per-lane partial row sums
    float lsum[4] = {0.f, 0.f, 0.f, 0.f};
#pragma unroll
    for (int tt = 0; tt < 4; tt++) {
#pragma unroll
      for (int r = 0; r < 4; r++) {
        float p = (pv[tt][r] > -1e29f) ? __expf(pv[tt][r] - mrow[r]) : 0.f;
        pv[tt][r] = p;
        lsum[r] += p;
      }
    }
#pragma unroll
    for (int r = 0; r < 4; r++) {
      float s = lsum[r];
      s += __shfl_xor(s, 1);
      s += __shfl_xor(s, 2);
      s += __shfl_xor(s, 4);
      s += __shfl_xor(s, 8);
      srow[r] = srow[r] * scale[r] + s;
    }
    // rescale running O
#pragma unroll
    for (int ot = 0; ot < 4; ot++) {
      f32x4 o = oacc[ot];
      o[0] *= scale[0]; o[1] *= scale[1]; o[2] *= scale[2]; o[3] *= scale[3];
      oacc[ot] = o;
    }
    // stage P (bf16) in LDS to re-layout into PV A-fragments (wave-private, in-order DS)
#pragma unroll
    for (int tt = 0; tt < 4; tt++)
#pragma unroll
      for (int r = 0; r < 4; r++)
        p_lds[w][lg * 4 + r][tt * 16 + lm] = f2bf(pv[tt][r]);

    bf16x8 pa0 = *(const bf16x8*)&p_lds[w][lm][lg * 8];
    bf16x8 pa1 = *(const bf16x8*)&p_lds[w][lm][32 + lg * 8];

    // ---- O += P V  (B-frag from Vt: contiguous 16B per lane) ----
#pragma unroll
    for (int ot = 0; ot < 4; ot++) {
      bf16x8 vb0 = *(const bf16x8*)&Vth[(ot * 16 + lm) * N + cb + lg * 8];
      bf16x8 vb1 = *(const bf16x8*)&Vth[(ot * 16 + lm) * N + cb + 32 + lg * 8];
      oacc[ot] = __builtin_amdgcn_mfma_f32_16x16x32_bf16(pa0, vb0, oacc[ot], 0, 0, 0);
      oacc[ot] = __builtin_amdgcn_mfma_f32_16x16x32_bf16(pa1, vb1, oacc[ot], 0, 0, 0);
    }
  }

  // ---- block merge of the 4 column-chunk partials ----
#pragma unroll
  for (int ot = 0; ot < 4; ot++)
#pragma unroll
    for (int r = 0; r < 4; r++)
      Om[w][lg * 4 + r][ot * 16 + lm] = oacc[ot][r];
  if (lm == 0) {
#pragma unroll
    for (int r = 0; r < 4; r++) {
      Ms[w][lg * 4 + r] = mrow[r];
      Ss[w][lg * 4 + r] = srow[r];
    }
  }
  __syncthreads();

#pragma unroll
  for (int k = 0; k < 4; k++) {
    int idx = tid + k * 256;
    int row = idx >> 6, col = idx & 63;
    float M = fmaxf(fmaxf(Ms[0][row], Ms[1][row]), fmaxf(Ms[2][row], Ms[3][row]));
    float S = 0.f, val = 0.f;
#pragma unroll
    for (int w2 = 0; w2 < 4; w2++) {
      float e = __expf(Ms[w2][row] - M);
      S += Ss[w2][row] * e;
      val += Om[w2][row][col] * e;
    }
    float o = (S > 0.f) ? val / S : 0.f;   // isolated rows -> exact 0 (matches att*adj!=0)
    o = fmaxf(o, 0.f) * rowmask[R0 + row]; // ReLU + padding-row mask
    out[(R0 + row) * (H * O) + h * O + col] = o;
  }
}

extern "C" void kernel_launch(void* const* d_in, const int* in_sizes, int n_in,
                              void* d_out, int out_size, void* d_ws, size_t ws_size,
                              hipStream_t stream) {
  const float* x   = (const float*)d_in[0];  // h [1,4096,128]
  const float* adj = (const float*)d_in[1];  // a [1,4096,4096]
  const float* wv  = (const float*)d_in[2];  // kernel      -> V
  const float* wq  = (const float*)d_in[3];  // attn_kernel -> Q (f_self)
  const float* wk  = (const float*)d_in[4];  // attn_kernel2-> K (f_other)
  float* out = (float*)d_out;

  u16* Q  = (u16*)d_ws;            // [4][4096][64] bf16  (2 MB)
  u16* K  = Q + H * N * O;         // [4][4096][64] bf16  (2 MB)
  u16* Vt = K + H * N * O;         // [4][64][4096] bf16  (2 MB)
  float* rmask = (float*)(Vt + H * N * O);  // [4096] f32

  proj_kernel<<<dim3(N / 64, 12), 256, 0, stream>>>(x, wv, wq, wk, Q, K, Vt);
  mask_kernel<<<dim3(N / 256), 256, 0, stream>>>(x, rmask);
  attn_kernel<<<dim3(N / 16, H), 256, 0, stream>>>(adj, Q, K, Vt, rmask, out);
}